// Round 1
// 432.248 us; speedup vs baseline: 1.0238x; 1.0238x over previous
//
#include <hip/hip_runtime.h>

typedef unsigned short ushort_t;
typedef unsigned int uint_t;
typedef __attribute__((ext_vector_type(8))) short short8;
typedef __attribute__((ext_vector_type(4))) float f32x4;
typedef __attribute__((ext_vector_type(4))) int i32x4;
typedef __attribute__((ext_vector_type(4))) uint_t u32x4;
typedef __attribute__((ext_vector_type(4))) ushort_t u16x4;

#define LRELU_SLOPE 0.2f

static __device__ __forceinline__ ushort_t f2bf(float f) {
    uint_t u = __builtin_bit_cast(uint_t, f);
    uint_t r = (u + 0x7fffu + ((u >> 16) & 1u)) >> 16;
    return (ushort_t)r;
}
static __device__ __forceinline__ uint4 pack8(float4 a, float4 b) {
    uint4 r;
    r.x = (uint_t)f2bf(a.x) | ((uint_t)f2bf(a.y) << 16);
    r.y = (uint_t)f2bf(a.z) | ((uint_t)f2bf(a.w) << 16);
    r.z = (uint_t)f2bf(b.x) | ((uint_t)f2bf(b.y) << 16);
    r.w = (uint_t)f2bf(b.z) | ((uint_t)f2bf(b.w) << 16);
    return r;
}

// ---------------------------------------------------------------------------
// K1: wh = h @ W^T + Wb (bf16) + s_src/s_dst f32 partials.
// NEW: wh is stored in the MFMA-fragment-tiled layout whB[jt][kh][d][kq][8]
// (jt = j>>6, kh = (j>>5)&1, kq = (j>>3)&3, s = j&7) so that K2's per-wave
// B-fragment read is one contiguous, fully-coalesced 1 KB block per
// (jt,kh,dq,nt) — no LDS staging needed in K2.
// ---------------------------------------------------------------------------
__launch_bounds__(256, 2)
__global__ void k1_gemm(const float* __restrict__ h, const float* __restrict__ W,
                        const float* __restrict__ Wb, const float* __restrict__ aw,
                        ushort_t* __restrict__ whB, float* __restrict__ s_src,
                        float* __restrict__ s_dst) {
    __shared__ __align__(16) ushort_t aT[256 * 72];  // W tile [o][k], stride 144 B
    __shared__ __align__(16) ushort_t bT[32 * 72];   // h tile [i][k]
    __shared__ float redLds[2][4][32];

    const int t = threadIdx.x;
    const int wv = t >> 6, ln = t & 63;
    const int i0 = blockIdx.x * 32;
    const int srow = t >> 3, sch = t & 7;  // staging: 32 rows/round, 8 lanes/row
    const int row0 = ln & 15, kq = ln >> 4;

    f32x4 acc[4][2];
#pragma unroll
    for (int mt = 0; mt < 4; ++mt)
#pragma unroll
        for (int nt = 0; nt < 2; ++nt) acc[mt][nt] = (f32x4){0.f, 0.f, 0.f, 0.f};

    for (int k0 = 0; k0 < 512; k0 += 64) {
        __syncthreads();
#pragma unroll
        for (int r = 0; r < 8; ++r) {
            const float* gp = W + (size_t)(r * 32 + srow) * 512 + k0 + sch * 8;
            float4 x0 = *(const float4*)gp;
            float4 x1 = *(const float4*)(gp + 4);
            *(uint4*)(aT + (r * 32 + srow) * 72 + sch * 8) = pack8(x0, x1);
        }
        {
            const float* gp = h + (size_t)(i0 + srow) * 512 + k0 + sch * 8;
            float4 x0 = *(const float4*)gp;
            float4 x1 = *(const float4*)(gp + 4);
            *(uint4*)(bT + srow * 72 + sch * 8) = pack8(x0, x1);
        }
        __syncthreads();
#pragma unroll
        for (int ks = 0; ks < 2; ++ks) {
            short8 b[2];
#pragma unroll
            for (int nt = 0; nt < 2; ++nt)
                b[nt] = *(const short8*)(bT + (nt * 16 + row0) * 72 + ks * 32 + kq * 8);
#pragma unroll
            for (int mt = 0; mt < 4; ++mt) {
                short8 a = *(const short8*)(aT + (wv * 64 + mt * 16 + row0) * 72 + ks * 32 + kq * 8);
#pragma unroll
                for (int nt = 0; nt < 2; ++nt)
                    acc[mt][nt] = __builtin_amdgcn_mfma_f32_16x16x32_bf16(a, b[nt], acc[mt][nt], 0, 0, 0);
            }
        }
    }

    // epilogue: bias, whB fragment-tiled bf16 store, s partials
    float psrc[2] = {0.f, 0.f}, pdst[2] = {0.f, 0.f};
#pragma unroll
    for (int mt = 0; mt < 4; ++mt) {
#pragma unroll
        for (int r = 0; r < 4; ++r) {
            const int o = wv * 64 + mt * 16 + (ln >> 4) * 4 + r;
            const float wbv = Wb[o];
            const float as = aw[o];
            const float ad = aw[256 + o];
#pragma unroll
            for (int nt = 0; nt < 2; ++nt) {
                const float v = acc[mt][nt][r] + wbv;
                psrc[nt] += v * as;
                pdst[nt] += v * ad;
                const int i = i0 + nt * 16 + (ln & 15);
                const int jt = i >> 6;
                const int khi = (i >> 5) & 1;
                const int kqi = (i >> 3) & 3;
                whB[((size_t)(jt * 2 + khi) * 256 + o) * 32 + kqi * 8 + (i & 7)] = f2bf(v);
            }
        }
    }
#pragma unroll
    for (int off = 16; off < 64; off <<= 1) {
#pragma unroll
        for (int nt = 0; nt < 2; ++nt) {
            psrc[nt] += __shfl_xor(psrc[nt], off, 64);
            pdst[nt] += __shfl_xor(pdst[nt], off, 64);
        }
    }
    if (ln < 16) {
#pragma unroll
        for (int nt = 0; nt < 2; ++nt) {
            redLds[0][wv][nt * 16 + ln] = psrc[nt];
            redLds[1][wv][nt * 16 + ln] = pdst[nt];
        }
    }
    __syncthreads();
    if (t < 32) {
        float s = 0.f;
#pragma unroll
        for (int w = 0; w < 4; ++w) s += redLds[0][w][t];
        s_src[i0 + t] = s;
    } else if (t < 64) {
        float s = 0.f;
#pragma unroll
        for (int w = 0; w < 4; ++w) s += redLds[1][w][t - 32];
        s_dst[i0 + t - 32] = s;
    }
}

// ---------------------------------------------------------------------------
// K2: per block: 32 i-rows x jlen. B-fragments (wh) come straight from the
// tiled whB layout as contiguous 1 KB per-wave global loads (L2-resident,
// 4 MB) — no wh LDS staging, no second barrier. Only the 32x64 p-tile goes
// through LDS (double-buffered). adj is streamed nontemporal so it doesn't
// evict whB from L2.
// ---------------------------------------------------------------------------
__launch_bounds__(512, 4)
__global__ void k2_attn(const int* __restrict__ adj, const ushort_t* __restrict__ whB,
                        const float* __restrict__ s_src, const float* __restrict__ s_dst,
                        const float* __restrict__ ab_p, float* __restrict__ out0,
                        float* __restrict__ out1, float* __restrict__ zp, int jsplit) {
    // pbuf: double-buffered p tile [2][32][72] (9.2 KB), unioned with the
    // 33.8 KB epilogue exchange (used only after all MFMA reads are done).
    __shared__ __align__(16) char smem[33792 + 128];
    ushort_t* pbuf = (ushort_t*)smem;
    float* exch = (float*)smem;
    float* zLds = (float*)(smem + 33792);

    const int t = threadIdx.x;
    const int wv = t >> 6, ln = t & 63;
    const int dq = wv & 3, kh = wv >> 2;
    const int row0 = ln & 15, kq = ln >> 4;
    const int split2 = (jsplit == 2);
    const int jb = split2 ? (int)(blockIdx.x & 1) : 0;
    const int ib = split2 ? (int)(blockIdx.x >> 1) : (int)blockIdx.x;
    const int i0 = ib * 32;
    const int jlen = split2 ? 4096 : 8192;
    const int jbase = jb * jlen;
    const int iters = jlen >> 6;
    const int prow = t >> 4, pjc = t & 15;  // p-compute: row 0..31, 4 j's each

    const float ab = ab_p[0];
    const float ssrc = s_src[i0 + prow];

    const int* aBase = adj + (size_t)(i0 + prow) * 8192 + jbase + pjc * 4;
    const float* sBase = s_dst + jbase + pjc * 4;
    // per-lane B-fragment pointer: contiguous 1 KB per (jt,kh,dq,nt) wave read
    const ushort_t* bBase = whB + ((size_t)(jbase >> 6) * 2 + kh) * 8192
                            + (dq * 64 + row0) * 32 + kq * 8;

    f32x4 acc[2][4];
#pragma unroll
    for (int mt = 0; mt < 2; ++mt)
#pragma unroll
        for (int nt = 0; nt < 4; ++nt) acc[mt][nt] = (f32x4){0.f, 0.f, 0.f, 0.f};
    float zacc = 0.f;

    // prefetch tile 0
    i32x4 Av = __builtin_nontemporal_load((const i32x4*)aBase);
    f32x4 Sv = *(const f32x4*)sBase;
    short8 Bv[4];
#pragma unroll
    for (int nt = 0; nt < 4; ++nt) Bv[nt] = *(const short8*)(bBase + nt * 512);

    for (int it = 0; it < iters; ++it) {
        const int itn = (it < iters - 1) ? it + 1 : it;
        const int jn = itn * 64;
        i32x4 Ac = Av;
        f32x4 Sc = Sv;
        short8 Bc[4];
#pragma unroll
        for (int nt = 0; nt < 4; ++nt) Bc[nt] = Bv[nt];
        // issue next-tile loads
        Av = __builtin_nontemporal_load((const i32x4*)(aBase + jn));
        Sv = *(const f32x4*)(sBase + jn);
        {
            const ushort_t* bN = bBase + (size_t)itn * 16384;
#pragma unroll
            for (int nt = 0; nt < 4; ++nt) Bv[nt] = *(const short8*)(bN + nt * 512);
        }

        // p tile for this iteration -> pbuf[it&1]
        {
            u16x4 pv4;
            float z4 = 0.f;
#pragma unroll
            for (int k = 0; k < 4; ++k) {
                float sc = ssrc + Sc[k] + ab;
                sc = sc > 0.f ? sc : LRELU_SLOPE * sc;
                sc = fminf(sc, 60.f);
                float pv = (Ac[k] > 0) ? __expf(sc) : 0.f;
                z4 += pv;
                pv4[k] = f2bf(pv);
            }
            zacc += z4;
            *(u16x4*)(pbuf + (it & 1) * 2304 + prow * 72 + pjc * 4) = pv4;
        }
        __syncthreads();  // p visible; MFMA(it-1) reads were on the other buffer
        {
            const ushort_t* pc = pbuf + (it & 1) * 2304;
            short8 a0 = *(const short8*)(pc + row0 * 72 + kh * 32 + kq * 8);
            short8 a1 = *(const short8*)(pc + (16 + row0) * 72 + kh * 32 + kq * 8);
#pragma unroll
            for (int nt = 0; nt < 4; ++nt) {
                acc[0][nt] = __builtin_amdgcn_mfma_f32_16x16x32_bf16(a0, Bc[nt], acc[0][nt], 0, 0, 0);
                acc[1][nt] = __builtin_amdgcn_mfma_f32_16x16x32_bf16(a1, Bc[nt], acc[1][nt], 0, 0, 0);
            }
        }
    }

    // per-row Z from the 16 consecutive lanes of each prow group
    zacc += __shfl_xor(zacc, 1, 64);
    zacc += __shfl_xor(zacc, 2, 64);
    zacc += __shfl_xor(zacc, 4, 64);
    zacc += __shfl_xor(zacc, 8, 64);
    if (split2) {
        if ((t & 15) == 0) zp[(size_t)jb * 8192 + i0 + prow] = zacc;
    } else {
        if ((t & 15) == 0) zLds[prow] = 1.0f / fmaxf(zacc, 1e-30f);
    }

    __syncthreads();  // all MFMA LDS reads done; pbuf region reusable as exchange
    if (kh == 1) {
        float* p = exch + (dq * 64 + ln) * 33;  // stride-33: conflict-free
#pragma unroll
        for (int mt = 0; mt < 2; ++mt)
#pragma unroll
            for (int nt = 0; nt < 4; ++nt)
#pragma unroll
                for (int r = 0; r < 4; ++r) p[mt * 16 + nt * 4 + r] = acc[mt][nt][r];
    }
    __syncthreads();
    if (kh == 0) {
        float* outp = (jb == 0) ? out0 : out1;
        const float* p = exch + (dq * 64 + ln) * 33;
#pragma unroll
        for (int mt = 0; mt < 2; ++mt)
#pragma unroll
            for (int nt = 0; nt < 4; ++nt)
#pragma unroll
                for (int r = 0; r < 4; ++r) {
                    const int il = mt * 16 + (ln >> 4) * 4 + r;
                    const int d = dq * 64 + nt * 16 + (ln & 15);
                    const float v = acc[mt][nt][r] + p[mt * 16 + nt * 4 + r];
                    if (split2)
                        outp[(size_t)(i0 + il) * 256 + d] = v;
                    else
                        outp[(size_t)(i0 + il) * 256 + d] = v * zLds[il];
                }
    }
}

// ---------------------------------------------------------------------------
// K3 (jsplit==2 only): out = (out + part) / (z0 + z1). grid 8192 x 256.
// ---------------------------------------------------------------------------
__global__ void k3_norm(float* __restrict__ out, const float* __restrict__ part,
                        const float* __restrict__ zp) {
    const int i = blockIdx.x, t = threadIdx.x;
    const float rz = 1.0f / fmaxf(zp[i] + zp[8192 + i], 1e-30f);
    const size_t idx = (size_t)i * 256 + t;
    out[idx] = (out[idx] + part[idx]) * rz;
}

extern "C" void kernel_launch(void* const* d_in, const int* in_sizes, int n_in, void* d_out,
                              int out_size, void* d_ws, size_t ws_size, hipStream_t stream) {
    // identify inputs by flat size (validated r7/r8)
    int order[16];
    for (int i = 0; i < n_in; ++i) order[i] = i;
    for (int a = 0; a < n_in; ++a)
        for (int b = a + 1; b < n_in; ++b)
            if (in_sizes[order[b]] < in_sizes[order[a]]) {
                int tmp = order[a]; order[a] = order[b]; order[b] = tmp;
            }
    const float* ab = (const float*)d_in[order[0]];
    const float* Wb = (const float*)d_in[order[1]];
    const float* aw = (const float*)d_in[order[2]];
    const float* Ww = (const float*)d_in[order[3]];
    const float* h = (const float*)d_in[order[4]];
    const int* adj = (const int*)d_in[order[5]];

    char* ws = (char*)d_ws;
    ushort_t* whB = (ushort_t*)ws;                 // 4 MB (fragment-tiled wh)
    float* ssrc = (float*)(ws + 4194304);          // 32 KB
    float* sdst = (float*)(ws + 4227072);          // 32 KB
    float* part = (float*)(ws + 4259840);          // 8 MB (jb=1 partial)
    float* zp = (float*)(ws + 12648448);           // 64 KB (2 x 8192 f32)
    const size_t need = 12713984;
    const int jsplit = (ws_size >= need) ? 2 : 1;

    hipLaunchKernelGGL(k1_gemm, dim3(256), dim3(256), 0, stream, h, Ww, Wb, aw, whB, ssrc, sdst);
    hipLaunchKernelGGL(k2_attn, dim3(256 * jsplit), dim3(512), 0, stream, adj, whB, ssrc, sdst,
                       ab, (float*)d_out, part, zp, jsplit);
    if (jsplit == 2)
        hipLaunchKernelGGL(k3_norm, dim3(8192), dim3(256), 0, stream, (float*)d_out, part, zp);
}

// Round 2
// 418.555 us; speedup vs baseline: 1.0573x; 1.0327x over previous
//
#include <hip/hip_runtime.h>

typedef unsigned short ushort_t;
typedef unsigned int uint_t;
typedef __attribute__((ext_vector_type(8))) short short8;
typedef __attribute__((ext_vector_type(4))) float f32x4;
typedef __attribute__((ext_vector_type(4))) int i32x4;
typedef __attribute__((ext_vector_type(4))) uint_t u32x4;
typedef __attribute__((ext_vector_type(4))) ushort_t u16x4;

#define LRELU_SLOPE 0.2f

static __device__ __forceinline__ ushort_t f2bf(float f) {
    uint_t u = __builtin_bit_cast(uint_t, f);
    uint_t r = (u + 0x7fffu + ((u >> 16) & 1u)) >> 16;
    return (ushort_t)r;
}
static __device__ __forceinline__ uint4 pack8(float4 a, float4 b) {
    uint4 r;
    r.x = (uint_t)f2bf(a.x) | ((uint_t)f2bf(a.y) << 16);
    r.y = (uint_t)f2bf(a.z) | ((uint_t)f2bf(a.w) << 16);
    r.z = (uint_t)f2bf(b.x) | ((uint_t)f2bf(b.y) << 16);
    r.w = (uint_t)f2bf(b.z) | ((uint_t)f2bf(b.w) << 16);
    return r;
}

// ---------------------------------------------------------------------------
// K1: wh = h @ W^T + Wb (bf16) + s_src/s_dst f32 partials. wh stored in the
// MFMA-fragment-tiled layout whB[jt][kh][d][kq][8] so K2's per-wave B-read is
// one contiguous coalesced block. Unchanged from round 1.
// ---------------------------------------------------------------------------
__launch_bounds__(256, 2)
__global__ void k1_gemm(const float* __restrict__ h, const float* __restrict__ W,
                        const float* __restrict__ Wb, const float* __restrict__ aw,
                        ushort_t* __restrict__ whB, float* __restrict__ s_src,
                        float* __restrict__ s_dst) {
    __shared__ __align__(16) ushort_t aT[256 * 72];  // W tile [o][k], stride 144 B
    __shared__ __align__(16) ushort_t bT[32 * 72];   // h tile [i][k]
    __shared__ float redLds[2][4][32];

    const int t = threadIdx.x;
    const int wv = t >> 6, ln = t & 63;
    const int i0 = blockIdx.x * 32;
    const int srow = t >> 3, sch = t & 7;
    const int row0 = ln & 15, kq = ln >> 4;

    f32x4 acc[4][2];
#pragma unroll
    for (int mt = 0; mt < 4; ++mt)
#pragma unroll
        for (int nt = 0; nt < 2; ++nt) acc[mt][nt] = (f32x4){0.f, 0.f, 0.f, 0.f};

    for (int k0 = 0; k0 < 512; k0 += 64) {
        __syncthreads();
#pragma unroll
        for (int r = 0; r < 8; ++r) {
            const float* gp = W + (size_t)(r * 32 + srow) * 512 + k0 + sch * 8;
            float4 x0 = *(const float4*)gp;
            float4 x1 = *(const float4*)(gp + 4);
            *(uint4*)(aT + (r * 32 + srow) * 72 + sch * 8) = pack8(x0, x1);
        }
        {
            const float* gp = h + (size_t)(i0 + srow) * 512 + k0 + sch * 8;
            float4 x0 = *(const float4*)gp;
            float4 x1 = *(const float4*)(gp + 4);
            *(uint4*)(bT + srow * 72 + sch * 8) = pack8(x0, x1);
        }
        __syncthreads();
#pragma unroll
        for (int ks = 0; ks < 2; ++ks) {
            short8 b[2];
#pragma unroll
            for (int nt = 0; nt < 2; ++nt)
                b[nt] = *(const short8*)(bT + (nt * 16 + row0) * 72 + ks * 32 + kq * 8);
#pragma unroll
            for (int mt = 0; mt < 4; ++mt) {
                short8 a = *(const short8*)(aT + (wv * 64 + mt * 16 + row0) * 72 + ks * 32 + kq * 8);
#pragma unroll
                for (int nt = 0; nt < 2; ++nt)
                    acc[mt][nt] = __builtin_amdgcn_mfma_f32_16x16x32_bf16(a, b[nt], acc[mt][nt], 0, 0, 0);
            }
        }
    }

    float psrc[2] = {0.f, 0.f}, pdst[2] = {0.f, 0.f};
#pragma unroll
    for (int mt = 0; mt < 4; ++mt) {
#pragma unroll
        for (int r = 0; r < 4; ++r) {
            const int o = wv * 64 + mt * 16 + (ln >> 4) * 4 + r;
            const float wbv = Wb[o];
            const float as = aw[o];
            const float ad = aw[256 + o];
#pragma unroll
            for (int nt = 0; nt < 2; ++nt) {
                const float v = acc[mt][nt][r] + wbv;
                psrc[nt] += v * as;
                pdst[nt] += v * ad;
                const int i = i0 + nt * 16 + (ln & 15);
                const int jt = i >> 6;
                const int khi = (i >> 5) & 1;
                const int kqi = (i >> 3) & 3;
                whB[((size_t)(jt * 2 + khi) * 256 + o) * 32 + kqi * 8 + (i & 7)] = f2bf(v);
            }
        }
    }
#pragma unroll
    for (int off = 16; off < 64; off <<= 1) {
#pragma unroll
        for (int nt = 0; nt < 2; ++nt) {
            psrc[nt] += __shfl_xor(psrc[nt], off, 64);
            pdst[nt] += __shfl_xor(pdst[nt], off, 64);
        }
    }
    if (ln < 16) {
#pragma unroll
        for (int nt = 0; nt < 2; ++nt) {
            redLds[0][wv][nt * 16 + ln] = psrc[nt];
            redLds[1][wv][nt * 16 + ln] = pdst[nt];
        }
    }
    __syncthreads();
    if (t < 32) {
        float s = 0.f;
#pragma unroll
        for (int w = 0; w < 4; ++w) s += redLds[0][w][t];
        s_src[i0 + t] = s;
    } else if (t < 64) {
        float s = 0.f;
#pragma unroll
        for (int w = 0; w < 4; ++w) s += redLds[1][w][t - 32];
        s_dst[i0 + t - 32] = s;
    }
}

// ---------------------------------------------------------------------------
// K2: NEW 64-row i-tiles (BM=64). grid = 128 ib x jsplit = 256 blocks =
// 1 block/CU, 8 waves. Halves whB cache traffic (1 GB -> 512 MB) and s_dst
// re-reads vs BM=32; doubles B-fragment register reuse (16 MFMA / 4 B-frags).
// Per thread: two p-rows (prow, prow+32). Accumulation order per output
// element unchanged -> bitwise-identical results.
// ---------------------------------------------------------------------------
__launch_bounds__(512, 2)
__global__ void k2_attn(const int* __restrict__ adj, const ushort_t* __restrict__ whB,
                        const float* __restrict__ s_src, const float* __restrict__ s_dst,
                        const float* __restrict__ ab_p, float* __restrict__ out0,
                        float* __restrict__ out1, float* __restrict__ zp, int jsplit) {
    // exch: 256 lanes * 65 f32 stride = 66560 B, unioned with pbuf
    // (2*64*72 ushort = 18432 B, double-buffered p tile). zLds after.
    __shared__ __align__(16) char smem[66560 + 256];
    ushort_t* pbuf = (ushort_t*)smem;
    float* exch = (float*)smem;
    float* zLds = (float*)(smem + 66560);

    const int t = threadIdx.x;
    const int wv = t >> 6, ln = t & 63;
    const int dq = wv & 3, kh = wv >> 2;
    const int row0 = ln & 15, kq = ln >> 4;
    const int split2 = (jsplit == 2);
    const int jb = split2 ? (int)(blockIdx.x & 1) : 0;
    const int ib = split2 ? (int)(blockIdx.x >> 1) : (int)blockIdx.x;
    const int i0 = ib * 64;
    const int jlen = split2 ? 4096 : 8192;
    const int jbase = jb * jlen;
    const int iters = jlen >> 6;
    const int prow = t >> 4, pjc = t & 15;  // p-compute: rows prow & prow+32, 4 j's

    const float ab = ab_p[0];
    const float ssrc0 = s_src[i0 + prow];
    const float ssrc1 = s_src[i0 + 32 + prow];

    const int* aBase0 = adj + (size_t)(i0 + prow) * 8192 + jbase + pjc * 4;
    const int* aBase1 = aBase0 + (size_t)32 * 8192;
    const float* sBase = s_dst + jbase + pjc * 4;
    // per-lane B-fragment pointer: contiguous 1 KB per (jt,kh,dq,nt) wave read
    const ushort_t* bBase = whB + ((size_t)(jbase >> 6) * 2 + kh) * 8192
                            + (dq * 64 + row0) * 32 + kq * 8;

    f32x4 acc[4][4];  // [mt][nt]
#pragma unroll
    for (int mt = 0; mt < 4; ++mt)
#pragma unroll
        for (int nt = 0; nt < 4; ++nt) acc[mt][nt] = (f32x4){0.f, 0.f, 0.f, 0.f};
    float zacc0 = 0.f, zacc1 = 0.f;

    // prefetch tile 0
    i32x4 Av0 = __builtin_nontemporal_load((const i32x4*)aBase0);
    i32x4 Av1 = __builtin_nontemporal_load((const i32x4*)aBase1);
    f32x4 Sv = *(const f32x4*)sBase;
    short8 Bv[4];
#pragma unroll
    for (int nt = 0; nt < 4; ++nt) Bv[nt] = *(const short8*)(bBase + nt * 512);

    for (int it = 0; it < iters; ++it) {
        const int itn = (it < iters - 1) ? it + 1 : it;
        const int jn = itn * 64;
        i32x4 Ac0 = Av0, Ac1 = Av1;
        f32x4 Sc = Sv;
        short8 Bc[4];
#pragma unroll
        for (int nt = 0; nt < 4; ++nt) Bc[nt] = Bv[nt];
        // issue next-tile loads
        Av0 = __builtin_nontemporal_load((const i32x4*)(aBase0 + jn));
        Av1 = __builtin_nontemporal_load((const i32x4*)(aBase1 + jn));
        Sv = *(const f32x4*)(sBase + jn);
        {
            const ushort_t* bN = bBase + (size_t)itn * 16384;
#pragma unroll
            for (int nt = 0; nt < 4; ++nt) Bv[nt] = *(const short8*)(bN + nt * 512);
        }

        // p tile (both rows) for this iteration -> pbuf[it&1]
        {
            ushort_t* pc = pbuf + (it & 1) * 4608;
            u16x4 pv4;
            float z4 = 0.f;
#pragma unroll
            for (int k = 0; k < 4; ++k) {
                float sc = ssrc0 + Sc[k] + ab;
                sc = sc > 0.f ? sc : LRELU_SLOPE * sc;
                sc = fminf(sc, 60.f);
                float pv = (Ac0[k] > 0) ? __expf(sc) : 0.f;
                z4 += pv;
                pv4[k] = f2bf(pv);
            }
            zacc0 += z4;
            *(u16x4*)(pc + prow * 72 + pjc * 4) = pv4;
            z4 = 0.f;
#pragma unroll
            for (int k = 0; k < 4; ++k) {
                float sc = ssrc1 + Sc[k] + ab;
                sc = sc > 0.f ? sc : LRELU_SLOPE * sc;
                sc = fminf(sc, 60.f);
                float pv = (Ac1[k] > 0) ? __expf(sc) : 0.f;
                z4 += pv;
                pv4[k] = f2bf(pv);
            }
            zacc1 += z4;
            *(u16x4*)(pc + (32 + prow) * 72 + pjc * 4) = pv4;
        }
        __syncthreads();  // p visible; MFMA(it-1) reads were on the other buffer
        {
            const ushort_t* pc = pbuf + (it & 1) * 4608;
#pragma unroll
            for (int mt = 0; mt < 4; ++mt) {
                short8 a = *(const short8*)(pc + (mt * 16 + row0) * 72 + kh * 32 + kq * 8);
#pragma unroll
                for (int nt = 0; nt < 4; ++nt)
                    acc[mt][nt] = __builtin_amdgcn_mfma_f32_16x16x32_bf16(a, Bc[nt], acc[mt][nt], 0, 0, 0);
            }
        }
    }

    // per-row Z from the 16 consecutive lanes of each prow group
    zacc0 += __shfl_xor(zacc0, 1, 64);
    zacc1 += __shfl_xor(zacc1, 1, 64);
    zacc0 += __shfl_xor(zacc0, 2, 64);
    zacc1 += __shfl_xor(zacc1, 2, 64);
    zacc0 += __shfl_xor(zacc0, 4, 64);
    zacc1 += __shfl_xor(zacc1, 4, 64);
    zacc0 += __shfl_xor(zacc0, 8, 64);
    zacc1 += __shfl_xor(zacc1, 8, 64);
    if ((t & 15) == 0) {
        if (split2) {
            zp[(size_t)jb * 8192 + i0 + prow] = zacc0;
            zp[(size_t)jb * 8192 + i0 + 32 + prow] = zacc1;
        } else {
            zLds[prow] = 1.0f / fmaxf(zacc0, 1e-30f);
            zLds[32 + prow] = 1.0f / fmaxf(zacc1, 1e-30f);
        }
    }

    __syncthreads();  // all MFMA LDS reads done; pbuf region reusable as exchange
    if (kh == 1) {
        float* p = exch + (dq * 64 + ln) * 65;  // stride-65: conflict-free
#pragma unroll
        for (int mt = 0; mt < 4; ++mt)
#pragma unroll
            for (int nt = 0; nt < 4; ++nt)
#pragma unroll
                for (int r = 0; r < 4; ++r) p[mt * 16 + nt * 4 + r] = acc[mt][nt][r];
    }
    __syncthreads();
    if (kh == 0) {
        float* outp = (jb == 0) ? out0 : out1;
        const float* p = exch + (dq * 64 + ln) * 65;
#pragma unroll
        for (int mt = 0; mt < 4; ++mt)
#pragma unroll
            for (int nt = 0; nt < 4; ++nt)
#pragma unroll
                for (int r = 0; r < 4; ++r) {
                    const int il = mt * 16 + (ln >> 4) * 4 + r;
                    const int d = dq * 64 + nt * 16 + (ln & 15);
                    const float v = acc[mt][nt][r] + p[mt * 16 + nt * 4 + r];
                    if (split2)
                        outp[(size_t)(i0 + il) * 256 + d] = v;
                    else
                        outp[(size_t)(i0 + il) * 256 + d] = v * zLds[il];
                }
    }
}

// ---------------------------------------------------------------------------
// K3 (jsplit==2 only): out = (out + part) / (z0 + z1). grid 8192 x 256.
// ---------------------------------------------------------------------------
__global__ void k3_norm(float* __restrict__ out, const float* __restrict__ part,
                        const float* __restrict__ zp) {
    const int i = blockIdx.x, t = threadIdx.x;
    const float rz = 1.0f / fmaxf(zp[i] + zp[8192 + i], 1e-30f);
    const size_t idx = (size_t)i * 256 + t;
    out[idx] = (out[idx] + part[idx]) * rz;
}

extern "C" void kernel_launch(void* const* d_in, const int* in_sizes, int n_in, void* d_out,
                              int out_size, void* d_ws, size_t ws_size, hipStream_t stream) {
    // identify inputs by flat size (validated r7/r8)
    int order[16];
    for (int i = 0; i < n_in; ++i) order[i] = i;
    for (int a = 0; a < n_in; ++a)
        for (int b = a + 1; b < n_in; ++b)
            if (in_sizes[order[b]] < in_sizes[order[a]]) {
                int tmp = order[a]; order[a] = order[b]; order[b] = tmp;
            }
    const float* ab = (const float*)d_in[order[0]];
    const float* Wb = (const float*)d_in[order[1]];
    const float* aw = (const float*)d_in[order[2]];
    const float* Ww = (const float*)d_in[order[3]];
    const float* h = (const float*)d_in[order[4]];
    const int* adj = (const int*)d_in[order[5]];

    char* ws = (char*)d_ws;
    ushort_t* whB = (ushort_t*)ws;                 // 4 MB (fragment-tiled wh)
    float* ssrc = (float*)(ws + 4194304);          // 32 KB
    float* sdst = (float*)(ws + 4227072);          // 32 KB
    float* part = (float*)(ws + 4259840);          // 8 MB (jb=1 partial)
    float* zp = (float*)(ws + 12648448);           // 64 KB (2 x 8192 f32)
    const size_t need = 12713984;
    const int jsplit = (ws_size >= need) ? 2 : 1;

    hipLaunchKernelGGL(k1_gemm, dim3(256), dim3(256), 0, stream, h, Ww, Wb, aw, whB, ssrc, sdst);
    hipLaunchKernelGGL(k2_attn, dim3(128 * jsplit), dim3(512), 0, stream, adj, whB, ssrc, sdst,
                       ab, (float*)d_out, part, zp, jsplit);
    if (jsplit == 2)
        hipLaunchKernelGGL(k3_norm, dim3(8192), dim3(256), 0, stream, (float*)d_out, part, zp);
}